// Round 9
// baseline (221.813 us; speedup 1.0000x reference)
//
#include <hip/hip_runtime.h>
#include <hip/hip_bf16.h>
#include <math.h>

#define N_CLS 16384
#define DDIM  128
#define CSHIFT 50.0f    // fixed shift; exp(-ap) folded back in log domain at finalize
#define LOG2E 1.4426950408889634f
#define NEGC2 (-72.13475204444817f)   // -CSHIFT*LOG2E: acc init via MFMA C-operand

#if __has_builtin(__builtin_amdgcn_exp2f)
#define EXP2(x) __builtin_amdgcn_exp2f(x)
#else
#define EXP2(x) exp2f(x)
#endif

typedef __attribute__((ext_vector_type(8))) short short8;   // 8 bf16 (4 VGPRs)
typedef __attribute__((ext_vector_type(4))) float f32x4;    // MFMA accumulator

__device__ __forceinline__ unsigned short f2bf(float f) {
    __hip_bfloat16 h = __float2bfloat16(f);
    return *(unsigned short*)&h;
}

// ---------------------------------------------------------------------------
// Fragment-major layout for mfma_f32_16x16x32_bf16 operands:
//   X[r][k] -> ((r>>4)*4 + (k>>5))*512 + (((k>>3)&3)*16 + (r&15))*8 + (k&7)
// one 16-row tile = 2048 shorts (4 kc x 512), one fragment = lane*8, 16 B/lane.
//
// prep: block = one 16-row tile; thread t writes short8 at tile*2048 + t*8
// (fully coalesced 16 B stores). t -> kc=t>>6, q=(t>>4)&3, m=t&15; reads
// x[2i(+1)][kc*32+q*8 .. +7] (32 B). ap via shfl + small LDS reduce.
//   ap[i] = dot(x[2i], x[2i+1])  (pair {anchor,pos}={2i,2i+1}, dot symmetric)
//   Afrag = anchor rows * LOG2E; Bfrag = negative rows. Zeroes out[0].
// ---------------------------------------------------------------------------
__global__ __launch_bounds__(256)
void prep_kernel(const float* __restrict__ x,
                 const int* __restrict__ aidx,
                 float* __restrict__ ap,
                 unsigned short* __restrict__ Afrag,
                 unsigned short* __restrict__ Bfrag,
                 float* __restrict__ out) {
    const int t = threadIdx.x;
    const int tl = blockIdx.x;              // 16-row tile index
    const int kc = t >> 6, q = (t >> 4) & 3, m = t & 15;
    const int col = kc * 32 + q * 8;
    const int i = tl * 16 + m;

    float fa[8], fb[8];
    *(float4*)&fa[0] = *(const float4*)(x + (2L * i) * DDIM + col);
    *(float4*)&fa[4] = *(const float4*)(x + (2L * i) * DDIM + col + 4);
    *(float4*)&fb[0] = *(const float4*)(x + (2L * i + 1) * DDIM + col);
    *(float4*)&fb[4] = *(const float4*)(x + (2L * i + 1) * DDIM + col + 4);
    const bool sel = (aidx[i] != 0);

    short8 As8, Bs8;
    float d = 0.0f;
    #pragma unroll
    for (int j = 0; j < 8; ++j) {
        const float av = sel ? fb[j] : fa[j];
        As8[j] = (short)f2bf(av * LOG2E);
        Bs8[j] = (short)f2bf(fb[j]);
        d += fa[j] * fb[j];
    }
    *(short8*)(Afrag + (long)tl * 2048 + t * 8) = As8;
    *(short8*)(Bfrag + (long)tl * 2048 + t * 8) = Bs8;

    // reduce dot over q (lanes xor 16,32 within wave), then over kc via LDS
    d += __shfl_xor(d, 16, 64);
    d += __shfl_xor(d, 32, 64);
    __shared__ float sap[4][16];
    if ((t & 63) < 16) sap[kc][t & 63] = d;
    __syncthreads();
    if (t < 16) ap[tl * 16 + t] = sap[0][t] + sap[1][t] + sap[2][t] + sap[3][t];
    if (t == 0 && tl == 0) out[0] = 0.0f;
}

// ---------------------------------------------------------------------------
// fused: block = (row-tile rt = bid>>3 [128 rows], col-octant oct = bid&7,
// XCD-aligned). NO LDS, NO barriers. Wave = 32 rows x full 128-col tile:
// af[2][4] = 32 VGPRs (round-8 lesson: af[4][4]=64 capped residency at
// ~2 waves/SIMD and MFMA/VALU wouldn't overlap). 128 nt-stages of
// {8 MFMA -> bank} || {8 exp2+add epilogue of previous bank}; b ping-pong
// prefetch one stage ahead; kc=0 MFMA takes cinit as C operand (free init).
// Diagonal excluded during accumulation (numerically mandatory).
// ---------------------------------------------------------------------------
__global__ __launch_bounds__(256, 4)
void fused_kernel(const unsigned short* __restrict__ Afrag,
                  const unsigned short* __restrict__ Bfrag,
                  float* __restrict__ partial) {
    const int tid = threadIdx.x;
    const int lane = tid & 63;
    const int w = tid >> 6;                 // wave 0..3 -> row quarter (32 rows)
    const int quad = lane >> 4;             // 0..3
    const int l15 = lane & 15;              // 0..15
    const int oct = blockIdx.x & 7;         // XCD-aligned column octant
    const int rt = blockIdx.x >> 3;         // row tile 0..127

    // hoist A fragments: tiles rt*8 + w*2 + mt, all 4 kc
    short8 af[2][4];
    {
        const unsigned short* abase =
            Afrag + ((long)(rt * 8 + w * 2) * 4) * 512 + lane * 8;
        #pragma unroll
        for (int mt = 0; mt < 2; ++mt)
            #pragma unroll
            for (int kc = 0; kc < 4; ++kc)
                af[mt][kc] = *(const short8*)(abase + (mt * 4 + kc) * 512);
    }

    // B octant base; stage s (= it*8+nt, 0..127) tile at s*2048 + kc*512
    const unsigned short* bbase = Bfrag + (long)oct * 262144 + lane * 8;

    const f32x4 cinit = (f32x4){NEGC2, NEGC2, NEGC2, NEGC2};
    float rs[2][4] = {};
    short8 b[2][4];
    f32x4 acc[2][2];

    // diag: rows rt*128+w*32+mt*16+e vs cols oct*2048+s*16... active only if
    // oct == rt>>4, at stages s = (rt&15)*8 + 2w + mt, masking elem e==l15.
    const bool canD = ((rt >> 4) == oct);
    const int itd = rt & 15;
    // mtd for a stage (dd = that it is diagonal, nt2 = its nt): 0/1 or -1
    auto mtdOf = [&](bool dd, int nt2) -> int {
        const int md = nt2 - 2 * w;
        return (dd && (md == 0 || md == 1)) ? md : -1;
    };
    auto epi = [&](f32x4 (&a)[2]) {
        #pragma unroll
        for (int mt = 0; mt < 2; ++mt)
            #pragma unroll
            for (int reg = 0; reg < 4; ++reg)
                rs[mt][reg] += EXP2(a[mt][reg]);
    };
    auto epiD = [&](f32x4 (&a)[2], int mtd) {
        #pragma unroll
        for (int mt = 0; mt < 2; ++mt)
            #pragma unroll
            for (int reg = 0; reg < 4; ++reg) {
                float e = EXP2(a[mt][reg]);
                if (mt == mtd && quad * 4 + reg == l15) e = 0.0f;
                rs[mt][reg] += e;
            }
    };

    // preload stage 0 into b[0]
    #pragma unroll
    for (int kc = 0; kc < 4; ++kc)
        b[0][kc] = *(const short8*)(bbase + kc * 512);

    bool dprev = false;
    for (int it = 0; it < 16; ++it) {
        const bool d = canD && (it == itd);
        const long itoff = (long)it * 16384;
        #pragma unroll
        for (int nt = 0; nt < 8; ++nt) {
            const int cb = nt & 1, ob = cb ^ 1;
            // prefetch next stage into b[ob] (clamped at the very last stage)
            const long nxt = (it == 15 && nt == 7) ? itoff + nt * 2048
                                                   : itoff + nt * 2048 + 2048;
            #pragma unroll
            for (int kc = 0; kc < 4; ++kc)
                b[ob][kc] = *(const short8*)(bbase + nxt + kc * 512);
            // 8 MFMAs into bank cb (C-operand init on kc=0)
            acc[cb][0] = __builtin_amdgcn_mfma_f32_16x16x32_bf16(
                af[0][0], b[cb][0], cinit, 0, 0, 0);
            acc[cb][1] = __builtin_amdgcn_mfma_f32_16x16x32_bf16(
                af[1][0], b[cb][0], cinit, 0, 0, 0);
            #pragma unroll
            for (int kc = 1; kc < 4; ++kc) {
                acc[cb][0] = __builtin_amdgcn_mfma_f32_16x16x32_bf16(
                    af[0][kc], b[cb][kc], acc[cb][0], 0, 0, 0);
                acc[cb][1] = __builtin_amdgcn_mfma_f32_16x16x32_bf16(
                    af[1][kc], b[cb][kc], acc[cb][1], 0, 0, 0);
            }
            // epilogue of previous stage (bank ob)
            if (it > 0 || nt > 0) {
                const int mtd = (nt == 0) ? mtdOf(dprev, 7) : mtdOf(d, nt - 1);
                if (mtd < 0) epi(acc[ob]); else epiD(acc[ob], mtd);
            }
        }
        dprev = d;
    }
    // drain stage 127 (bank 1)
    {
        const int mtd = mtdOf(dprev, 7);
        if (mtd < 0) epi(acc[1]); else epiD(acc[1], mtd);
    }

    // cross-l15 reduce; one plain store per (row, oct)
    const int rowBase = rt * 128 + w * 32;
    #pragma unroll
    for (int mt = 0; mt < 2; ++mt)
        #pragma unroll
        for (int reg = 0; reg < 4; ++reg) {
            float v = rs[mt][reg];
            v += __shfl_xor(v, 1, 64);
            v += __shfl_xor(v, 2, 64);
            v += __shfl_xor(v, 4, 64);
            v += __shfl_xor(v, 8, 64);
            if (l15 == 0)
                partial[(long)oct * N_CLS + rowBase + mt * 16 + quad * 4 + reg] = v;
        }
}

// ---------------------------------------------------------------------------
// finalize: per row s = sum of 8 octant partials (= sum_j exp(S_ij - C), j!=i);
// loss = log1p(s * exp(C - ap)) via u = log(s) + C - ap; block-sum; atomicAdd.
// ---------------------------------------------------------------------------
__global__ __launch_bounds__(256)
void finalize_kernel(const float* __restrict__ partial,
                     const float* __restrict__ ap,
                     float* __restrict__ out) {
    __shared__ float red[256];
    const int t = threadIdx.x;
    const int row = blockIdx.x * 256 + t;
    float s = 0.0f;
    #pragma unroll
    for (int p = 0; p < 8; ++p) s += partial[(long)p * N_CLS + row];
    const float u = logf(s) + (CSHIFT - ap[row]);
    const float loss = (u > 25.0f) ? u : log1pf(__expf(u));
    red[t] = loss;
    __syncthreads();
    for (int st = 128; st > 0; st >>= 1) {
        if (t < st) red[t] += red[t + st];
        __syncthreads();
    }
    if (t == 0) atomicAdd(out, red[0]);
}

extern "C" void kernel_launch(void* const* d_in, const int* in_sizes, int n_in,
                              void* d_out, int out_size, void* d_ws, size_t ws_size,
                              hipStream_t stream) {
    const float* x    = (const float*)d_in[0];
    const int*   aidx = (const int*)d_in[1];
    // d_in[2] (pos_idx) derivable; unused.

    char* ws = (char*)d_ws;
    float* ap             = (float*)(ws);                                   // 64 KB
    float* partial        = (float*)(ws + 131072);                          // 512 KB
    unsigned short* Afrag = (unsigned short*)(ws + 131072 + 1048576);       // 4 MB
    unsigned short* Bfrag = (unsigned short*)(ws + 131072 + 1048576 + 4194304); // 4 MB

    prep_kernel<<<N_CLS / 16, 256, 0, stream>>>(x, aidx, ap, Afrag, Bfrag, (float*)d_out);
    fused_kernel<<<1024, 256, 0, stream>>>(Afrag, Bfrag, partial);
    finalize_kernel<<<64, 256, 0, stream>>>(partial, ap, (float*)d_out);
}

// Round 10
// 133.232 us; speedup vs baseline: 1.6649x; 1.6649x over previous
//
#include <hip/hip_runtime.h>
#include <hip/hip_bf16.h>
#include <math.h>

#define N_CLS 16384
#define DDIM  128
#define CSHIFT 50.0f    // fixed shift; exp(-ap) folded back in log domain at finalize
#define LOG2E 1.4426950408889634f
#define NEGC2 (-72.13475204444817f)   // -CSHIFT*LOG2E: acc init via MFMA C-operand

#if __has_builtin(__builtin_amdgcn_exp2f)
#define EXP2(x) __builtin_amdgcn_exp2f(x)
#else
#define EXP2(x) exp2f(x)
#endif

typedef __attribute__((ext_vector_type(8))) short short8;   // 8 bf16 (4 VGPRs)
typedef __attribute__((ext_vector_type(4))) float f32x4;    // MFMA accumulator

__device__ __forceinline__ unsigned short f2bf(float f) {
    __hip_bfloat16 h = __float2bfloat16(f);
    return *(unsigned short*)&h;
}

// ---------------------------------------------------------------------------
// Fragment-major layout for mfma_f32_16x16x32_bf16 operands:
//   X[r][k] -> ((r>>4)*4 + (k>>5))*512 + (((k>>3)&3)*16 + (r&15))*8 + (k&7)
// one 16-row tile = 2048 shorts (4 kc x 512); a wave's fragment = lane*8.
//
// prep (r9 coalesced version): block = one 16-row tile; thread t writes short8
// at tile*2048 + t*8 (fully sequential 16 B stores). t -> kc=t>>6, q=(t>>4)&3,
// m=t&15; reads x[2i(+1)][kc*32+q*8 .. +7]. ap via shfl + small LDS reduce.
//   ap[i] = dot(x[2i], x[2i+1])  (pair {anchor,pos}={2i,2i+1}, dot symmetric)
//   Afrag = anchor rows * LOG2E; Bfrag = negative rows. Zeroes out[0].
// ---------------------------------------------------------------------------
__global__ __launch_bounds__(256)
void prep_kernel(const float* __restrict__ x,
                 const int* __restrict__ aidx,
                 float* __restrict__ ap,
                 unsigned short* __restrict__ Afrag,
                 unsigned short* __restrict__ Bfrag,
                 float* __restrict__ out) {
    const int t = threadIdx.x;
    const int tl = blockIdx.x;              // 16-row tile index
    const int kc = t >> 6, q = (t >> 4) & 3, m = t & 15;
    const int col = kc * 32 + q * 8;
    const int i = tl * 16 + m;

    float fa[8], fb[8];
    *(float4*)&fa[0] = *(const float4*)(x + (2L * i) * DDIM + col);
    *(float4*)&fa[4] = *(const float4*)(x + (2L * i) * DDIM + col + 4);
    *(float4*)&fb[0] = *(const float4*)(x + (2L * i + 1) * DDIM + col);
    *(float4*)&fb[4] = *(const float4*)(x + (2L * i + 1) * DDIM + col + 4);
    const bool sel = (aidx[i] != 0);

    short8 As8, Bs8;
    float d = 0.0f;
    #pragma unroll
    for (int j = 0; j < 8; ++j) {
        const float av = sel ? fb[j] : fa[j];
        As8[j] = (short)f2bf(av * LOG2E);
        Bs8[j] = (short)f2bf(fb[j]);
        d += fa[j] * fb[j];
    }
    *(short8*)(Afrag + (long)tl * 2048 + t * 8) = As8;
    *(short8*)(Bfrag + (long)tl * 2048 + t * 8) = Bs8;

    // reduce dot over q (xor 16,32 within wave), then over kc (wave idx) in LDS
    d += __shfl_xor(d, 16, 64);
    d += __shfl_xor(d, 32, 64);
    __shared__ float sap[4][16];
    if ((t & 63) < 16) sap[kc][t & 63] = d;
    __syncthreads();
    if (t < 16) ap[tl * 16 + t] = sap[0][t] + sap[1][t] + sap[2][t] + sap[3][t];
    if (t == 0 && tl == 0) out[0] = 0.0f;
}

// ---------------------------------------------------------------------------
// fused (r8 version verbatim — local optimum: 64x64 wave, af[4][4] hoisted,
// nt-granularity two-bank pipeline, no forced occupancy. r9 lesson: forcing
// 4 waves/SIMD via launch_bounds spills; halving wave N-width halves the
// MFMA:load ratio. Do not touch without watching WRITE_SIZE.)
// block = (row-tile rt = bid>>3, col-octant oct = bid&7, XCD-aligned).
// NO LDS, NO barriers. Diagonal excluded during accumulation.
// ---------------------------------------------------------------------------
__global__ __launch_bounds__(256, 2)
void fused_kernel(const unsigned short* __restrict__ Afrag,
                  const unsigned short* __restrict__ Bfrag,
                  float* __restrict__ partial) {
    const int tid = threadIdx.x;
    const int lane = tid & 63;
    const int w = tid >> 6;                 // wave 0..3
    const int quad = lane >> 4;             // 0..3
    const int l15 = lane & 15;              // 0..15
    const int oct = blockIdx.x & 7;         // XCD-aligned column octant
    const int rt = blockIdx.x >> 3;         // row tile 0..127
    const int wm2 = w >> 1;                 // wave row half
    const int wh = w & 1;                   // wave col half

    // hoist A fragments (rows rt*128 + wm2*64 + mt*16, all 4 kc)
    short8 af[4][4];
    {
        const unsigned short* abase =
            Afrag + ((long)(rt * 8 + wm2 * 4) * 4) * 512 + lane * 8;
        #pragma unroll
        for (int mt = 0; mt < 4; ++mt)
            #pragma unroll
            for (int kc = 0; kc < 4; ++kc)
                af[mt][kc] = *(const short8*)(abase + (mt * 4 + kc) * 512);
    }

    const unsigned short* bbase =
        Bfrag + ((long)(oct * 128 + wh * 4) * 4) * 512 + lane * 8;

    const f32x4 cinit = (f32x4){NEGC2, NEGC2, NEGC2, NEGC2};
    float rs[4][4] = {};
    short8 bP[4], bQ[4];
    f32x4 accA[4], accB[4];

    // diag stage: ct == rt possible only when rt>>4 == oct; then it = rt&15.
    const bool canDiag = ((rt >> 4) == oct) && (wm2 == wh);
    const int itd = canDiag ? (rt & 15) : -1;

    auto mfma4 = [&](f32x4 (&acc)[4], short8 (&b)[4]) {
        #pragma unroll
        for (int mt = 0; mt < 4; ++mt)
            acc[mt] = __builtin_amdgcn_mfma_f32_16x16x32_bf16(
                af[mt][0], b[0], cinit, 0, 0, 0);
        #pragma unroll
        for (int kc = 1; kc < 4; ++kc)
            #pragma unroll
            for (int mt = 0; mt < 4; ++mt)
                acc[mt] = __builtin_amdgcn_mfma_f32_16x16x32_bf16(
                    af[mt][kc], b[kc], acc[mt], 0, 0, 0);
    };
    auto epi = [&](f32x4 (&acc)[4]) {
        #pragma unroll
        for (int mt = 0; mt < 4; ++mt)
            #pragma unroll
            for (int reg = 0; reg < 4; ++reg)
                rs[mt][reg] += EXP2(acc[mt][reg]);
    };
    auto epiD = [&](f32x4 (&acc)[4], int nt) {
        #pragma unroll
        for (int mt = 0; mt < 4; ++mt)
            #pragma unroll
            for (int reg = 0; reg < 4; ++reg) {
                float e = EXP2(acc[mt][reg]);
                if (mt == nt) e = (quad * 4 + reg == l15) ? 0.0f : e;
                rs[mt][reg] += e;
            }
    };

    // preload b for stage (it=0, nt=0)
    #pragma unroll
    for (int kc = 0; kc < 4; ++kc)
        bP[kc] = *(const short8*)(bbase + kc * 512);

    bool dprev = false;
    for (int it = 0; it < 16; ++it) {
        const unsigned short* p1 = bbase + (long)it * 16384;
        const bool d = (it == itd);

        // stage nt=0: acc A <- bP ; prefetch (it,1) -> bQ ; epi stage (it-1,3)
        #pragma unroll
        for (int kc = 0; kc < 4; ++kc)
            bQ[kc] = *(const short8*)(p1 + 2048 + kc * 512);
        mfma4(accA, bP);
        if (it > 0) { if (dprev) epiD(accB, 3); else epi(accB); }

        // stage nt=1: acc B <- bQ ; prefetch (it,2) -> bP ; epi stage (it,0)
        #pragma unroll
        for (int kc = 0; kc < 4; ++kc)
            bP[kc] = *(const short8*)(p1 + 4096 + kc * 512);
        mfma4(accB, bQ);
        if (d) epiD(accA, 0); else epi(accA);

        // stage nt=2: acc A <- bP ; prefetch (it,3) -> bQ ; epi stage (it,1)
        #pragma unroll
        for (int kc = 0; kc < 4; ++kc)
            bQ[kc] = *(const short8*)(p1 + 6144 + kc * 512);
        mfma4(accA, bP);
        if (d) epiD(accB, 1); else epi(accB);

        // stage nt=3: acc B <- bQ ; prefetch (it+1,0) -> bP ; epi stage (it,2)
        const unsigned short* p2 = bbase + (long)((it < 15) ? it + 1 : it) * 16384;
        #pragma unroll
        for (int kc = 0; kc < 4; ++kc)
            bP[kc] = *(const short8*)(p2 + kc * 512);
        mfma4(accB, bQ);
        if (d) epiD(accA, 2); else epi(accA);

        dprev = d;
    }
    // drain: epi of stage (15,3)
    if (dprev) epiD(accB, 3); else epi(accB);

    // cross-l15 reduce, plain store into slot (oct, col-half)
    const int slot = oct * 2 + wh;          // 16 slots
    const int rowBase = rt * 128 + wm2 * 64;
    #pragma unroll
    for (int mt = 0; mt < 4; ++mt)
        #pragma unroll
        for (int reg = 0; reg < 4; ++reg) {
            float v = rs[mt][reg];
            v += __shfl_xor(v, 1, 64);
            v += __shfl_xor(v, 2, 64);
            v += __shfl_xor(v, 4, 64);
            v += __shfl_xor(v, 8, 64);
            if (l15 == 0)
                partial[(long)slot * N_CLS + rowBase + mt * 16 + quad * 4 + reg] = v;
        }
}

// ---------------------------------------------------------------------------
// finalize: per row s = sum of 16 slot partials (= sum_j exp(S_ij - C), j!=i);
// loss = log1p(s * exp(C - ap)) via u = log(s) + C - ap; block-sum; atomicAdd.
// ---------------------------------------------------------------------------
__global__ __launch_bounds__(256)
void finalize_kernel(const float* __restrict__ partial,
                     const float* __restrict__ ap,
                     float* __restrict__ out) {
    __shared__ float red[256];
    const int t = threadIdx.x;
    const int row = blockIdx.x * 256 + t;
    float s = 0.0f;
    #pragma unroll
    for (int p = 0; p < 16; ++p) s += partial[(long)p * N_CLS + row];
    const float u = logf(s) + (CSHIFT - ap[row]);
    const float loss = (u > 25.0f) ? u : log1pf(__expf(u));
    red[t] = loss;
    __syncthreads();
    for (int st = 128; st > 0; st >>= 1) {
        if (t < st) red[t] += red[t + st];
        __syncthreads();
    }
    if (t == 0) atomicAdd(out, red[0]);
}

extern "C" void kernel_launch(void* const* d_in, const int* in_sizes, int n_in,
                              void* d_out, int out_size, void* d_ws, size_t ws_size,
                              hipStream_t stream) {
    const float* x    = (const float*)d_in[0];
    const int*   aidx = (const int*)d_in[1];
    // d_in[2] (pos_idx) derivable; unused.

    char* ws = (char*)d_ws;
    float* ap             = (float*)(ws);                                   // 64 KB
    float* partial        = (float*)(ws + 131072);                          // 1 MB
    unsigned short* Afrag = (unsigned short*)(ws + 131072 + 1048576);       // 4 MB
    unsigned short* Bfrag = (unsigned short*)(ws + 131072 + 1048576 + 4194304); // 4 MB

    prep_kernel<<<N_CLS / 16, 256, 0, stream>>>(x, aidx, ap, Afrag, Bfrag, (float*)d_out);
    fused_kernel<<<1024, 256, 0, stream>>>(Afrag, Bfrag, partial);
    finalize_kernel<<<64, 256, 0, stream>>>(partial, ap, (float*)d_out);
}